// Round 8
// baseline (431.611 us; speedup 1.0000x reference)
//
#include <hip/hip_runtime.h>
#include <hip/hip_bf16.h>
#include <stdint.h>

#define TOKENS 16384
#define DMODEL 2048
#define NEXP   64

// output layout (flat f32, reference return order)
#define OFF_IDX    0
#define OFF_PROBS  (TOKENS * 2)
#define OFF_LOGITS (TOKENS * 4)
#define OFF_LOSS   (OFF_LOGITS + TOKENS * NEXP)
#define OFF_CNT    (OFF_LOSS + 1)

#define KC 64   // k floats staged per chunk
#define TG 64   // tokens per block

// ws layout: [0..63] prob colsums, [64..127] counts, partials s=1..KS-1 at
// float offset 256 + (s-1)*TOKENS*NEXP
#define WS_PART_OFF 256

__device__ __forceinline__ void gload16(const float* src, const float* ldsdst) {
    // global -> LDS direct copy, 16 B per lane; dest = wave-uniform base + lane*16
    auto g1 = (const __attribute__((address_space(1))) uint32_t*)(uintptr_t)src;
    auto l3 = (__attribute__((address_space(3))) uint32_t*)(uintptr_t)ldsdst;
    __builtin_amdgcn_global_load_lds(g1, l3, 16, 0, 0);
}

// K1: logits partial GEMM. grid = 256*KS blocks, 256 thr (4 waves).
// block = 64 tokens x 64 experts x (2048/KS) k.  wave = 16 experts.
// lane = token. x staged coalesced into LDS (XOR-swizzled 16B slots).
//
// R6 lesson (VGPR=44/SGPR=112, VALUBusy=24%): wave-uniform w addresses got
// scalar-promoted to s_load; SMEM is out-of-order -> lgkmcnt(0) per use,
// shared with ds_read -> the whole pipeline serialized. Fix: opaque VGPR
// zero in the gw base defeats the uniformity proof, forcing vector
// global_load_dwordx4 (in-order, counted vmcnt, independent of lgkmcnt).
template<int KS>
__global__ __launch_bounds__(256, 4) void k1_logits(
    const float* __restrict__ x, const float* __restrict__ gw,
    float* __restrict__ out, float* __restrict__ ws)
{
    __shared__ float xs[2][TG * KC];   // 2 x 16 KB double buffer
    const int tid  = threadIdx.x;
    const int lane = tid & 63;
    const int wv   = __builtin_amdgcn_readfirstlane(tid >> 6);  // wave-uniform (LDS bases)
    const int bid  = blockIdx.x;
    const int tg   = bid & 255;        // token group
    const int s    = bid >> 8;         // k-slice id
    const int t0   = tg * TG;
    constexpr int KW  = DMODEL / KS;
    constexpr int NCH = KW / KC;
    const int kbase = s * KW;

    // Opaque zero: compiler cannot prove it's 0 -> w addresses look per-lane
    // -> vector loads (vmcnt path), NOT s_load (lgkmcnt path).
    int opaque_zero;
    asm volatile("v_mov_b32 %0, 0" : "=v"(opaque_zero));
    const float* __restrict__ gwv = gw + opaque_zero;

    float acc[16];
#pragma unroll
    for (int i = 0; i < 16; ++i) acc[i] = 0.f;

    // ---- stage chunk 0 into xs[0] ----
#pragma unroll
    for (int jj = 0; jj < 4; ++jj) {
        const int rbase = wv * 16 + jj * 4;
        const int r = rbase + (lane >> 4);
        const int m = lane & 15;
        const int u = m ^ (r & 15);
        const float* src = x + (size_t)(t0 + r) * DMODEL + kbase + u * 4;
        gload16(src, &xs[0][rbase * KC]);
    }

    for (int cc = 0; cc < NCH; ++cc) {
        __syncthreads();   // staged chunk cc ready; prev compute done
        const int b = cc & 1;
        if (cc + 1 < NCH) {
#pragma unroll
            for (int jj = 0; jj < 4; ++jj) {
                const int rbase = wv * 16 + jj * 4;
                const int r = rbase + (lane >> 4);
                const int m = lane & 15;
                const int u = m ^ (r & 15);
                const float* src = x + (size_t)(t0 + r) * DMODEL + kbase + (cc + 1) * KC + u * 4;
                gload16(src, &xs[b ^ 1][rbase * KC]);
            }
        }
        // ---- compute chunk cc ----
        float4 xv[2][4];
#pragma unroll
        for (int q = 0; q < 4; ++q)
            xv[0][q] = *(const float4*)&xs[b][lane * KC + ((q ^ (lane & 15)) << 2)];
        float4 wp[3][4];
        const float* wk = gwv + kbase + cc * KC;
        {
            const float* p0 = wk + (size_t)(wv * 16 + 0) * DMODEL;
            const float* p1 = wk + (size_t)(wv * 16 + 1) * DMODEL;
#pragma unroll
            for (int q = 0; q < 4; ++q) { wp[0][q] = *(const float4*)(p0 + q * 4);
                                          wp[1][q] = *(const float4*)(p1 + q * 4); }
        }
#pragma unroll
        for (int gi = 0; gi < 64; ++gi) {   // fully unrolled: all array idx static
            const int g = gi >> 4, i = gi & 15;
            if (i == 0 && g < 3) {   // prefetch next x group from LDS (lgkmcnt)
#pragma unroll
                for (int q = 0; q < 4; ++q) {
                    const int u = (g + 1) * 4 + q;
                    xv[(g + 1) & 1][q] = *(const float4*)&xs[b][lane * KC + ((u ^ (lane & 15)) << 2)];
                }
            }
            if (gi + 2 < 64) {       // w pipeline, 2 experts ahead (vmcnt, in-order)
                const int gi2 = gi + 2, g2 = gi2 >> 4, i2 = gi2 & 15;
                const float* p = wk + (size_t)(wv * 16 + i2) * DMODEL + g2 * 16;
#pragma unroll
                for (int q = 0; q < 4; ++q) wp[gi2 % 3][q] = *(const float4*)(p + q * 4);
            }
            const float4* W = wp[gi % 3];
            const float4* X = xv[g & 1];
            float a = acc[i];
            a = fmaf(X[0].x, W[0].x, a); a = fmaf(X[0].y, W[0].y, a);
            a = fmaf(X[0].z, W[0].z, a); a = fmaf(X[0].w, W[0].w, a);
            a = fmaf(X[1].x, W[1].x, a); a = fmaf(X[1].y, W[1].y, a);
            a = fmaf(X[1].z, W[1].z, a); a = fmaf(X[1].w, W[1].w, a);
            a = fmaf(X[2].x, W[2].x, a); a = fmaf(X[2].y, W[2].y, a);
            a = fmaf(X[2].z, W[2].z, a); a = fmaf(X[2].w, W[2].w, a);
            a = fmaf(X[3].x, W[3].x, a); a = fmaf(X[3].y, W[3].y, a);
            a = fmaf(X[3].z, W[3].z, a); a = fmaf(X[3].w, W[3].w, a);
            acc[i] = a;
        }
    }

    // ---- write partial [64t][64e] via LDS transpose (coalesced global stores) ----
    __syncthreads();
    float* tr = &xs[0][0];
#pragma unroll
    for (int i = 0; i < 16; ++i) {
        const int e = wv * 16 + i;
        tr[lane * 64 + (e ^ lane)] = acc[i];   // XOR swizzle: 2-way bank alias only
    }
    __syncthreads();
    float* dst = (s == 0) ? (out + OFF_LOGITS)
                          : (ws + WS_PART_OFF + (size_t)(s - 1) * TOKENS * NEXP);
#pragma unroll
    for (int c2 = 0; c2 < 4; ++c2) {
        const int flat = c2 * 1024 + tid * 4;
        const int r = flat >> 6, cg = flat & 63;
        float4 v;
        v.x = tr[r * 64 + ((cg + 0) ^ r)];
        v.y = tr[r * 64 + ((cg + 1) ^ r)];
        v.z = tr[r * 64 + ((cg + 2) ^ r)];
        v.w = tr[r * 64 + ((cg + 3) ^ r)];
        *(float4*)(dst + (size_t)t0 * 64 + flat) = v;
    }
}

// K2: fixed-order partial sum -> logits; top-2, probs, softmax colsums, counts.
// grid = 256 blocks (64 tokens each), 256 thr.
template<int KS>
__global__ __launch_bounds__(256) void k2_topk(float* __restrict__ out,
                                               float* __restrict__ ws)
{
    __shared__ float l2[64 * 64];   // 16 KB
    __shared__ float colacc[64];
    const int tid = threadIdx.x;
    const int blk = blockIdx.x;
    const int base = blk * 4096;    // floats into logits
    if (tid < 64) colacc[tid] = 0.f;

    // phase A: deterministic fixed-order sum of K-slice partials
#pragma unroll
    for (int c2 = 0; c2 < 4; ++c2) {
        const int flat = c2 * 1024 + tid * 4;
        float4 v = *(const float4*)(out + OFF_LOGITS + base + flat);
#pragma unroll
        for (int s = 1; s < KS; ++s) {
            const float4 p = *(const float4*)(ws + WS_PART_OFF +
                               (size_t)(s - 1) * TOKENS * NEXP + base + flat);
            v.x += p.x; v.y += p.y; v.z += p.z; v.w += p.w;
        }
        if (KS > 1) *(float4*)(out + OFF_LOGITS + base + flat) = v;
        const int r = flat >> 6, cg = flat & 63;
        l2[r * 64 + ((cg + 0) ^ r)] = v.x;
        l2[r * 64 + ((cg + 1) ^ r)] = v.y;
        l2[r * 64 + ((cg + 2) ^ r)] = v.z;
        l2[r * 64 + ((cg + 3) ^ r)] = v.w;
    }
    __syncthreads();

    // phase B: one token per lane of wave 0
    if (tid < 64) {
        const int t = tid;
        float v1 = -3.0e38f, v2 = -3.0e38f;
        int i1 = 0, i2 = 0;
#pragma unroll
        for (int e = 0; e < 64; ++e) {
            const float lv = l2[t * 64 + (e ^ t)];
            if (lv > v1) { v2 = v1; i2 = i1; v1 = lv; i1 = e; }
            else if (lv > v2) { v2 = lv; i2 = e; }
        }
        const int token = blk * 64 + t;
        out[OFF_IDX + token * 2 + 0] = (float)i1;
        out[OFF_IDX + token * 2 + 1] = (float)i2;
        const float p1 = 1.f / (1.f + __expf(v2 - v1));
        out[OFF_PROBS + token * 2 + 0] = p1;
        out[OFF_PROBS + token * 2 + 1] = 1.f - p1;

        float ssum = 0.f;
#pragma unroll
        for (int e = 0; e < 64; ++e) ssum += __expf(l2[t * 64 + (e ^ t)] - v1);
        const float inv = 1.f / ssum;
#pragma unroll
        for (int e = 0; e < 64; ++e) {
            const int a = t * 64 + (e ^ t);
            l2[a] = __expf(l2[a] - v1) * inv;   // overwrite with probs
        }
        // counts: ballot histogram across the 64 token-lanes
        float myc = 0.f;
        for (int e = 0; e < 64; ++e) {
            const int c = __popcll(__ballot(i1 == e)) + __popcll(__ballot(i2 == e));
            if (e == t) myc = (float)c;
        }
        atomicAdd(ws + 64 + t, myc);
    }
    __syncthreads();

    // prob column sums (for balance loss): each thread sums 16 rows of one column
    {
        const int col = tid & 63, rb = tid >> 6;
        float sm = 0.f;
#pragma unroll
        for (int rr = 0; rr < 16; ++rr) {
            const int r = rb * 16 + rr;
            sm += l2[r * 64 + (col ^ r)];
        }
        atomicAdd(&colacc[col], sm);
    }
    __syncthreads();
    if (tid < 64) atomicAdd(ws + tid, colacc[tid]);
}

__global__ void finalize_kernel(const float* __restrict__ ws,
                                float* __restrict__ out)
{
    const int e = threadIdx.x;  // 64 threads
    const float cnt  = ws[64 + e];
    const float psum = ws[e];
    float term = (cnt * (1.f / (TOKENS * 2.f))) * (psum * (1.f / (float)TOKENS))
                 * ((float)NEXP * 0.01f);
#pragma unroll
    for (int off = 32; off > 0; off >>= 1) term += __shfl_down(term, off);
    if (e == 0) out[OFF_LOSS] = term;
    out[OFF_CNT + e] = cnt;
}

extern "C" void kernel_launch(void* const* d_in, const int* in_sizes, int n_in,
                              void* d_out, int out_size, void* d_ws, size_t ws_size,
                              hipStream_t stream)
{
    (void)in_sizes; (void)n_in; (void)out_size;
    const float* x  = (const float*)d_in[0];
    const float* gw = (const float*)d_in[1];
    float* out = (float*)d_out;
    float* ws  = (float*)d_ws;

    hipMemsetAsync(d_ws, 0, 512, stream);   // colsum + count accumulators

    const size_t need = (WS_PART_OFF + 3ull * TOKENS * NEXP) * 4ull;
    if (ws_size >= need) {
        k1_logits<4><<<1024, 256, 0, stream>>>(x, gw, out, ws);
        k2_topk<4><<<256, 256, 0, stream>>>(out, ws);
    } else {
        k1_logits<1><<<256, 256, 0, stream>>>(x, gw, out, ws);
        k2_topk<1><<<256, 256, 0, stream>>>(out, ws);
    }
    finalize_kernel<<<1, 64, 0, stream>>>(ws, out);
}

// Round 9
// 262.942 us; speedup vs baseline: 1.6415x; 1.6415x over previous
//
#include <hip/hip_runtime.h>
#include <hip/hip_bf16.h>
#include <stdint.h>

#define TOKENS 16384
#define DMODEL 2048
#define NEXP   64

// output layout (flat f32, reference return order)
#define OFF_IDX    0
#define OFF_PROBS  (TOKENS * 2)
#define OFF_LOGITS (TOKENS * 4)
#define OFF_LOSS   (OFF_LOGITS + TOKENS * NEXP)
#define OFF_CNT    (OFF_LOSS + 1)

#define TG  128   // tokens per block (2 per lane)
#define KC  32    // k floats staged per chunk

// ws layout: [0..63] prob colsums, [64..127] counts, partials s=1..KS-1 at
// float offset 256 + (s-1)*TOKENS*NEXP
#define WS_PART_OFF 256

__device__ __forceinline__ void gload16(const float* src, const float* ldsdst) {
    // global -> LDS direct copy, 16 B per lane; dest = wave-uniform base + lane*16
    auto g1 = (const __attribute__((address_space(1))) uint32_t*)(uintptr_t)src;
    auto l3 = (__attribute__((address_space(3))) uint32_t*)(uintptr_t)ldsdst;
    __builtin_amdgcn_global_load_lds(g1, l3, 16, 0, 0);
}

// K1 history: R6 (w via s_load: SMEM out-of-order -> lgkmcnt(0) per use shared
// with ds_read -> 24% VALU). R8 (w via forced vector loads: compiler sank
// loads to use, no pipeline -> 22% VALU). R9: BOTH operands staged in LDS via
// global_load_lds; inner loop is pure ds_read + FMA, which the compiler
// schedules with fine-grained counted lgkmcnt (m97-proven). 2 tokens/lane
// doubles w reuse: one w float4 broadcast-read feeds 8 FMAs.
//
// block = 128 tokens x 64 experts x (2048/KS) k, 256 thr (4 waves).
// wave = 16 experts x 128 tokens. lane: tokens (lane, 64+lane).
// LDS 48 KB: x dbuf 2x16KB (XOR-swizzled granules), w dbuf 2x8KB (linear).
template<int KS>
__global__ __launch_bounds__(256, 2) void k1_logits(
    const float* __restrict__ x, const float* __restrict__ gw,
    float* __restrict__ out, float* __restrict__ ws)
{
    __shared__ float pool[12288];   // [0,8192): x bufs; [8192,12288): w bufs
    const int tid  = threadIdx.x;
    const int lane = tid & 63;
    const int wv   = __builtin_amdgcn_readfirstlane(tid >> 6);
    const int bid  = blockIdx.x;
    const int tg   = bid & 127;        // token group (128 tokens)
    const int s    = bid >> 7;         // k-slice id
    const int t0   = tg * TG;
    constexpr int KW  = DMODEL / KS;   // k per slice
    constexpr int NCH = KW / KC;       // chunks per slice
    const int kbase = s * KW;
    const int l7 = lane & 7;

    float acc0[16], acc1[16];
#pragma unroll
    for (int i = 0; i < 16; ++i) { acc0[i] = 0.f; acc1[i] = 0.f; }

    // ---- staging helpers (all gload_lds: dest wave-uniform base + lane*16) ----
    // x chunk: 1024 granules of 4 floats. granule G=(t<<3)|cp holds global
    // granule c = cp ^ (t&7) of token row t  (XOR swizzle, both-sides rule).
    auto stage_x = [&](int cc, int d) {
#pragma unroll
        for (int j = 0; j < 4; ++j) {
            const int Gbase = j * 256 + wv * 64;            // wave-uniform
            const int G = Gbase + lane;
            const int t = G >> 3;
            const int c = (G & 7) ^ (t & 7);
            const float* src = x + (size_t)(t0 + t) * DMODEL + kbase + cc * KC + c * 4;
            gload16(src, &pool[d * 4096 + Gbase * 4]);
        }
    };
    // w chunk: 512 granules, linear [e][k]: granule H=(e<<3)|c.
    auto stage_w = [&](int cc, int d) {
#pragma unroll
        for (int j = 0; j < 2; ++j) {
            const int Hbase = j * 256 + wv * 64;
            const int H = Hbase + lane;
            const int e = H >> 3;
            const int c = H & 7;
            const float* src = gw + (size_t)e * DMODEL + kbase + cc * KC + c * 4;
            gload16(src, &pool[8192 + d * 2048 + Hbase * 4]);
        }
    };

    // ---- prologue: stage chunk 0 ----
    stage_x(0, 0);
    stage_w(0, 0);

    for (int cc = 0; cc < NCH; ++cc) {
        __syncthreads();   // staged chunk cc ready (vmcnt drained); buf b^1 free
        const int b = cc & 1;
        if (cc + 1 < NCH) { stage_x(cc + 1, b ^ 1); stage_w(cc + 1, b ^ 1); }

        const float* xb = &pool[b * 4096];
        const float* wb = &pool[8192 + b * 2048];
#pragma unroll
        for (int g = 0; g < 8; ++g) {
            const float4 xa = *(const float4*)&xb[lane * KC + ((g ^ l7) << 2)];
            const float4 xc = *(const float4*)&xb[(64 + lane) * KC + ((g ^ l7) << 2)];
#pragma unroll
            for (int i = 0; i < 16; ++i) {
                const float4 w4 = *(const float4*)&wb[(wv * 16 + i) * KC + (g << 2)];
                float a0 = acc0[i], a1 = acc1[i];
                a0 = fmaf(xa.x, w4.x, a0); a1 = fmaf(xc.x, w4.x, a1);
                a0 = fmaf(xa.y, w4.y, a0); a1 = fmaf(xc.y, w4.y, a1);
                a0 = fmaf(xa.z, w4.z, a0); a1 = fmaf(xc.z, w4.z, a1);
                a0 = fmaf(xa.w, w4.w, a0); a1 = fmaf(xc.w, w4.w, a1);
                acc0[i] = a0; acc1[i] = a1;
            }
        }
    }

    // ---- epilogue: [128t][64e] transpose via LDS, coalesced global stores ----
    __syncthreads();
    float* tr = pool;   // needs 8192 floats
#pragma unroll
    for (int i = 0; i < 16; ++i) {
        const int e = wv * 16 + i;
        tr[lane * 64 + (e ^ lane)] = acc0[i];          // row=lane
        tr[(64 + lane) * 64 + (e ^ lane)] = acc1[i];   // row=64+lane, (64+lane)&63==lane
    }
    __syncthreads();
    float* dst = (s == 0) ? (out + OFF_LOGITS)
                          : (ws + WS_PART_OFF + (size_t)(s - 1) * TOKENS * NEXP);
#pragma unroll
    for (int c2 = 0; c2 < 8; ++c2) {
        const int flat = c2 * 1024 + tid * 4;
        const int r = flat >> 6, cg = flat & 63;
        float4 v;
        v.x = tr[r * 64 + ((cg + 0) ^ (r & 63))];
        v.y = tr[r * 64 + ((cg + 1) ^ (r & 63))];
        v.z = tr[r * 64 + ((cg + 2) ^ (r & 63))];
        v.w = tr[r * 64 + ((cg + 3) ^ (r & 63))];
        *(float4*)(dst + (size_t)t0 * 64 + flat) = v;
    }
}

// K2: fixed-order partial sum -> logits; top-2, probs, softmax colsums, counts.
// grid = 256 blocks (64 tokens each), 256 thr.  (independent of k1's TG)
template<int KS>
__global__ __launch_bounds__(256) void k2_topk(float* __restrict__ out,
                                               float* __restrict__ ws)
{
    __shared__ float l2[64 * 64];   // 16 KB
    __shared__ float colacc[64];
    const int tid = threadIdx.x;
    const int blk = blockIdx.x;
    const int base = blk * 4096;    // floats into logits
    if (tid < 64) colacc[tid] = 0.f;

    // phase A: deterministic fixed-order sum of K-slice partials
#pragma unroll
    for (int c2 = 0; c2 < 4; ++c2) {
        const int flat = c2 * 1024 + tid * 4;
        float4 v = *(const float4*)(out + OFF_LOGITS + base + flat);
#pragma unroll
        for (int s = 1; s < KS; ++s) {
            const float4 p = *(const float4*)(ws + WS_PART_OFF +
                               (size_t)(s - 1) * TOKENS * NEXP + base + flat);
            v.x += p.x; v.y += p.y; v.z += p.z; v.w += p.w;
        }
        if (KS > 1) *(float4*)(out + OFF_LOGITS + base + flat) = v;
        const int r = flat >> 6, cg = flat & 63;
        l2[r * 64 + ((cg + 0) ^ r)] = v.x;
        l2[r * 64 + ((cg + 1) ^ r)] = v.y;
        l2[r * 64 + ((cg + 2) ^ r)] = v.z;
        l2[r * 64 + ((cg + 3) ^ r)] = v.w;
    }
    __syncthreads();

    // phase B: one token per lane of wave 0
    if (tid < 64) {
        const int t = tid;
        float v1 = -3.0e38f, v2 = -3.0e38f;
        int i1 = 0, i2 = 0;
#pragma unroll
        for (int e = 0; e < 64; ++e) {
            const float lv = l2[t * 64 + (e ^ t)];
            if (lv > v1) { v2 = v1; i2 = i1; v1 = lv; i1 = e; }
            else if (lv > v2) { v2 = lv; i2 = e; }
        }
        const int token = blk * 64 + t;
        out[OFF_IDX + token * 2 + 0] = (float)i1;
        out[OFF_IDX + token * 2 + 1] = (float)i2;
        const float p1 = 1.f / (1.f + __expf(v2 - v1));
        out[OFF_PROBS + token * 2 + 0] = p1;
        out[OFF_PROBS + token * 2 + 1] = 1.f - p1;

        float ssum = 0.f;
#pragma unroll
        for (int e = 0; e < 64; ++e) ssum += __expf(l2[t * 64 + (e ^ t)] - v1);
        const float inv = 1.f / ssum;
#pragma unroll
        for (int e = 0; e < 64; ++e) {
            const int a = t * 64 + (e ^ t);
            l2[a] = __expf(l2[a] - v1) * inv;   // overwrite with probs
        }
        // counts: ballot histogram across the 64 token-lanes
        float myc = 0.f;
        for (int e = 0; e < 64; ++e) {
            const int c = __popcll(__ballot(i1 == e)) + __popcll(__ballot(i2 == e));
            if (e == t) myc = (float)c;
        }
        atomicAdd(ws + 64 + t, myc);
    }
    __syncthreads();

    // prob column sums (for balance loss): each thread sums 16 rows of one column
    {
        const int col = tid & 63, rb = tid >> 6;
        float sm = 0.f;
#pragma unroll
        for (int rr = 0; rr < 16; ++rr) {
            const int r = rb * 16 + rr;
            sm += l2[r * 64 + (col ^ r)];
        }
        atomicAdd(&colacc[col], sm);
    }
    __syncthreads();
    if (tid < 64) atomicAdd(ws + tid, colacc[tid]);
}

__global__ void finalize_kernel(const float* __restrict__ ws,
                                float* __restrict__ out)
{
    const int e = threadIdx.x;  // 64 threads
    const float cnt  = ws[64 + e];
    const float psum = ws[e];
    float term = (cnt * (1.f / (TOKENS * 2.f))) * (psum * (1.f / (float)TOKENS))
                 * ((float)NEXP * 0.01f);
#pragma unroll
    for (int off = 32; off > 0; off >>= 1) term += __shfl_down(term, off);
    if (e == 0) out[OFF_LOSS] = term;
    out[OFF_CNT + e] = cnt;
}

extern "C" void kernel_launch(void* const* d_in, const int* in_sizes, int n_in,
                              void* d_out, int out_size, void* d_ws, size_t ws_size,
                              hipStream_t stream)
{
    (void)in_sizes; (void)n_in; (void)out_size;
    const float* x  = (const float*)d_in[0];
    const float* gw = (const float*)d_in[1];
    float* out = (float*)d_out;
    float* ws  = (float*)d_ws;

    hipMemsetAsync(d_ws, 0, 512, stream);   // colsum + count accumulators

    const size_t need = (WS_PART_OFF + 3ull * TOKENS * NEXP) * 4ull;
    if (ws_size >= need) {
        k1_logits<4><<<128 * 4, 256, 0, stream>>>(x, gw, out, ws);
        k2_topk<4><<<256, 256, 0, stream>>>(out, ws);
    } else {
        k1_logits<1><<<128, 256, 0, stream>>>(x, gw, out, ws);
        k2_topk<1><<<256, 256, 0, stream>>>(out, ws);
    }
    finalize_kernel<<<1, 64, 0, stream>>>(ws, out);
}